// Round 1
// baseline (1850.229 us; speedup 1.0000x reference)
//
#include <hip/hip_runtime.h>
#include <math.h>

#define C     128
#define NB    16
#define NCPL  11
#define RCUT  5.0f
#define EPSF  1e-8f
#define TE    8      // edges per block

typedef float f4_t __attribute__((ext_vector_type(4)));
typedef float f2_t __attribute__((ext_vector_type(2)));

__global__ __launch_bounds__(256, 3)
void edge_update(
    const float* __restrict__ node0, const float* __restrict__ node1,
    const float* __restrict__ node2, const float* __restrict__ edge0,
    const float* __restrict__ edge1, const float* __restrict__ edge2,
    const float* __restrict__ rij,   const float* __restrict__ W_rad,
    const float* __restrict__ U0,    const float* __restrict__ b0,
    const float* __restrict__ U1,    const float* __restrict__ U2,
    const float* __restrict__ Wg0,   const float* __restrict__ bg0,
    const float* __restrict__ Wg1,   const float* __restrict__ bg1,
    const float* __restrict__ Wg2,   const float* __restrict__ bg2,
    const int*   __restrict__ idx_j,
    float* __restrict__ out0, float* __restrict__ out1, float* __restrict__ out2,
    int E)
{
    // m_sh[e][j][c]: j=0 -> m0 ; j=1..3 -> m1[:,a] ; j=4..12 -> m2[:,a*3+b]
    __shared__ __align__(16) float m_sh[TE][13][C];   // 53248 B
    __shared__ float rbf_sh[TE][NB];
    __shared__ float rhat_sh[TE][4];
    __shared__ int   jidx_sh[TE];

    const int tid = threadIdx.x;
    const long e0 = (long)blockIdx.x * TE;

    // ---------------- phase 0: per-edge scalars ----------------
    if (tid < TE) {
        long eg = e0 + tid; if (eg >= E) eg = E - 1;
        jidx_sh[tid] = idx_j[eg];
    }
    if (tid < TE * NB) {
        const int e = tid >> 4, b = tid & (NB - 1);
        long eg = e0 + e; if (eg >= E) eg = E - 1;
        const float x = rij[eg*3+0], y = rij[eg*3+1], z = rij[eg*3+2];
        const float d   = sqrtf(x*x + y*y + z*z);
        const float inv = 1.0f / (d + EPSF);
        if (b == 0) {
            rhat_sh[e][0] = x*inv; rhat_sh[e][1] = y*inv; rhat_sh[e][2] = z*inv;
        }
        const float env = (d < RCUT) ? 0.5f*(cosf((float)M_PI * d / RCUT) + 1.0f) : 0.0f;
        rbf_sh[e][b] = sinf((float)(b+1) * (float)M_PI * d / RCUT) * inv * env;
    }
    __syncthreads();

    // ---------------- phase 1: build m0/m1/m2 in LDS ----------------
    {
        const int c = tid & (C - 1);
        const int h = tid >> 7;                 // 0/1 ; edges h*4 .. h*4+3

        float w[4][NCPL];
        #pragma unroll
        for (int q = 0; q < 4; ++q)
            #pragma unroll
            for (int k = 0; k < NCPL; ++k) w[q][k] = 0.f;

        for (int b = 0; b < NB; ++b) {
            float rb[4];
            #pragma unroll
            for (int q = 0; q < 4; ++q) rb[q] = rbf_sh[h*4+q][b];
            #pragma unroll
            for (int k = 0; k < NCPL; ++k) {
                const float wr = W_rad[(k*NB + b)*C + c];
                #pragma unroll
                for (int q = 0; q < 4; ++q) w[q][k] += rb[q] * wr;
            }
        }

        #pragma unroll
        for (int q = 0; q < 4; ++q) {
            const int  e = h*4 + q;
            const long j = jidx_sh[e];
            const float rx = rhat_sh[e][0], ry = rhat_sh[e][1], rz = rhat_sh[e][2];

            const float x0v = node0[j*C + c];
            const float* p1 = node1 + (j*C + c)*3;
            const float x1x = p1[0], x1y = p1[1], x1z = p1[2];
            const float* p2 = node2 + (j*C + c)*9;
            float x2v[9];
            #pragma unroll
            for (int i = 0; i < 9; ++i) x2v[i] = p2[i];

            const float x1r  = x1x*rx + x1y*ry + x1z*rz;
            const float x2r0 = x2v[0]*rx + x2v[1]*ry + x2v[2]*rz;
            const float x2r1 = x2v[3]*rx + x2v[4]*ry + x2v[5]*rz;
            const float x2r2 = x2v[6]*rx + x2v[7]*ry + x2v[8]*rz;
            const float x2rr = x2r0*rx + x2r1*ry + x2r2*rz;

            m_sh[e][0][c] = w[q][0]*x0v + w[q][4]*x1r + w[q][9]*x2rr;

            const float r3[3]   = {rx, ry, rz};
            const float x1v3[3] = {x1x, x1y, x1z};
            const float x2rv[3] = {x2r0, x2r1, x2r2};
            #pragma unroll
            for (int a = 0; a < 3; ++a)
                m_sh[e][1+a][c] = w[q][1]*x0v*r3[a] + w[q][3]*x1v3[a]
                                + w[q][6]*x1r*r3[a] + w[q][8]*x2rv[a];
            #pragma unroll
            for (int a = 0; a < 3; ++a)
                #pragma unroll
                for (int b = 0; b < 3; ++b)
                    m_sh[e][4+a*3+b][c] = w[q][2]*x0v*r3[a]*r3[b] + w[q][5]*x1v3[a]*r3[b]
                                        + w[q][7]*x2v[a*3+b]      + w[q][10]*x2rv[a]*r3[b];
        }
    }
    __syncthreads();

    // ---------------- phase 2: channel mixing + gates + residual ----------------
    const int fp = tid & 63;
    const int f0 = fp << 1;            // two consecutive output channels
    const int g  = tid >> 6;           // 0..3 ; edges {2g, 2g+1}
    const int ea = g*2, eb = g*2 + 1;

    // ---- A: m0' = m0 @ U0 + b0 (overwrite m_sh[.][0][.]) ----
    {
        float acc[2][2] = {{0.f,0.f},{0.f,0.f}};
        for (int cc = 0; cc < C; cc += 4) {
            const f4_t ma = *(const f4_t*)&m_sh[ea][0][cc];
            const f4_t mb = *(const f4_t*)&m_sh[eb][0][cc];
            #pragma unroll
            for (int u = 0; u < 4; ++u) {
                const f2_t wv = *(const f2_t*)&U0[(long)(cc+u)*C + f0];
                acc[0][0] += ma[u]*wv.x; acc[0][1] += ma[u]*wv.y;
                acc[1][0] += mb[u]*wv.x; acc[1][1] += mb[u]*wv.y;
            }
        }
        const float bb0 = b0[f0], bb1 = b0[f0+1];
        __syncthreads();                       // all m0 reads done
        m_sh[ea][0][f0]   = acc[0][0] + bb0;
        m_sh[ea][0][f0+1] = acc[0][1] + bb1;
        m_sh[eb][0][f0]   = acc[1][0] + bb0;
        m_sh[eb][0][f0+1] = acc[1][1] + bb1;
        __syncthreads();
    }

    // ---- B: three gate matvecs on m0', silu, out0, keep gates in regs ----
    float gate1[2][2], gate2[2][2];
    {
        float acc[3][2][2] = {};
        for (int cc = 0; cc < C; cc += 4) {
            const f4_t ma = *(const f4_t*)&m_sh[ea][0][cc];
            const f4_t mb = *(const f4_t*)&m_sh[eb][0][cc];
            #pragma unroll
            for (int u = 0; u < 4; ++u) {
                const f2_t w0v = *(const f2_t*)&Wg0[(long)(cc+u)*C + f0];
                const f2_t w1v = *(const f2_t*)&Wg1[(long)(cc+u)*C + f0];
                const f2_t w2v = *(const f2_t*)&Wg2[(long)(cc+u)*C + f0];
                acc[0][0][0] += ma[u]*w0v.x; acc[0][0][1] += ma[u]*w0v.y;
                acc[0][1][0] += mb[u]*w0v.x; acc[0][1][1] += mb[u]*w0v.y;
                acc[1][0][0] += ma[u]*w1v.x; acc[1][0][1] += ma[u]*w1v.y;
                acc[1][1][0] += mb[u]*w1v.x; acc[1][1][1] += mb[u]*w1v.y;
                acc[2][0][0] += ma[u]*w2v.x; acc[2][0][1] += ma[u]*w2v.y;
                acc[2][1][0] += mb[u]*w2v.x; acc[2][1][1] += mb[u]*w2v.y;
            }
        }
        const float bgv0[2] = {bg0[f0], bg0[f0+1]};
        const float bgv1[2] = {bg1[f0], bg1[f0+1]};
        const float bgv2[2] = {bg2[f0], bg2[f0+1]};
        #pragma unroll
        for (int i = 0; i < 2; ++i) {
            const long eg = e0 + g*2 + i;
            #pragma unroll
            for (int df = 0; df < 2; ++df) {
                const float z0 = acc[0][i][df] + bgv0[df];
                const float z1 = acc[1][i][df] + bgv1[df];
                const float z2 = acc[2][i][df] + bgv2[df];
                const float s0 = z0 / (1.0f + expf(-z0));
                gate1[i][df]   = z1 / (1.0f + expf(-z1));
                gate2[i][df]   = z2 / (1.0f + expf(-z2));
                if (eg < E)
                    out0[eg*C + f0 + df] = edge0[eg*C + f0 + df] + s0;
            }
        }
    }

    // ---- C: way-1: m1' = einsum(m1, U1), gate, residual ----
    {
        float acc[3][2][2] = {};
        for (int cc = 0; cc < C; cc += 4) {
            f4_t mv[3][2];
            #pragma unroll
            for (int a = 0; a < 3; ++a) {
                mv[a][0] = *(const f4_t*)&m_sh[ea][1+a][cc];
                mv[a][1] = *(const f4_t*)&m_sh[eb][1+a][cc];
            }
            #pragma unroll
            for (int u = 0; u < 4; ++u) {
                const f2_t wv = *(const f2_t*)&U1[(long)(cc+u)*C + f0];
                #pragma unroll
                for (int a = 0; a < 3; ++a) {
                    acc[a][0][0] += mv[a][0][u]*wv.x; acc[a][0][1] += mv[a][0][u]*wv.y;
                    acc[a][1][0] += mv[a][1][u]*wv.x; acc[a][1][1] += mv[a][1][u]*wv.y;
                }
            }
        }
        #pragma unroll
        for (int i = 0; i < 2; ++i) {
            const long eg = e0 + g*2 + i;
            if (eg < E) {
                #pragma unroll
                for (int df = 0; df < 2; ++df) {
                    const int f = f0 + df;
                    const float gv = gate1[i][df];
                    const long base = (eg*(long)C + f)*3;
                    #pragma unroll
                    for (int a = 0; a < 3; ++a)
                        out1[base+a] = edge1[base+a] + acc[a][i][df]*gv;
                }
            }
        }
    }

    // ---- D: way-2: three passes of 3 components each ----
    for (int p = 0; p < 3; ++p) {
        float acc[3][2][2] = {};
        for (int cc = 0; cc < C; cc += 4) {
            f4_t mv[3][2];
            #pragma unroll
            for (int a = 0; a < 3; ++a) {
                mv[a][0] = *(const f4_t*)&m_sh[ea][4+p*3+a][cc];
                mv[a][1] = *(const f4_t*)&m_sh[eb][4+p*3+a][cc];
            }
            #pragma unroll
            for (int u = 0; u < 4; ++u) {
                const f2_t wv = *(const f2_t*)&U2[(long)(cc+u)*C + f0];
                #pragma unroll
                for (int a = 0; a < 3; ++a) {
                    acc[a][0][0] += mv[a][0][u]*wv.x; acc[a][0][1] += mv[a][0][u]*wv.y;
                    acc[a][1][0] += mv[a][1][u]*wv.x; acc[a][1][1] += mv[a][1][u]*wv.y;
                }
            }
        }
        #pragma unroll
        for (int i = 0; i < 2; ++i) {
            const long eg = e0 + g*2 + i;
            if (eg < E) {
                #pragma unroll
                for (int df = 0; df < 2; ++df) {
                    const int f = f0 + df;
                    const float gv = gate2[i][df];
                    const long base = (eg*(long)C + f)*9 + p*3;
                    #pragma unroll
                    for (int a = 0; a < 3; ++a)
                        out2[base+a] = edge2[base+a] + acc[a][i][df]*gv;
                }
            }
        }
    }
}

extern "C" void kernel_launch(void* const* d_in, const int* in_sizes, int n_in,
                              void* d_out, int out_size, void* d_ws, size_t ws_size,
                              hipStream_t stream) {
    const float* node0 = (const float*)d_in[0];
    const float* node1 = (const float*)d_in[1];
    const float* node2 = (const float*)d_in[2];
    const float* edge0 = (const float*)d_in[3];
    const float* edge1 = (const float*)d_in[4];
    const float* edge2 = (const float*)d_in[5];
    const float* rijp  = (const float*)d_in[6];
    const float* W_rad = (const float*)d_in[7];
    const float* U0    = (const float*)d_in[8];
    const float* b0    = (const float*)d_in[9];
    const float* U1    = (const float*)d_in[10];
    const float* U2    = (const float*)d_in[11];
    const float* Wg0   = (const float*)d_in[12];
    const float* bg0   = (const float*)d_in[13];
    const float* Wg1   = (const float*)d_in[14];
    const float* bg1   = (const float*)d_in[15];
    const float* Wg2   = (const float*)d_in[16];
    const float* bg2   = (const float*)d_in[17];
    const int*   idxj  = (const int*)d_in[18];

    const int E = in_sizes[6] / 3;

    float* out0 = (float*)d_out;
    float* out1 = out0 + (size_t)E * C;
    float* out2 = out1 + (size_t)E * C * 3;

    const int nblocks = (E + TE - 1) / TE;
    hipLaunchKernelGGL(edge_update, dim3(nblocks), dim3(256), 0, stream,
                       node0, node1, node2, edge0, edge1, edge2, rijp, W_rad,
                       U0, b0, U1, U2, Wg0, bg0, Wg1, bg1, Wg2, bg2, idxj,
                       out0, out1, out2, E);
}